// Round 1
// baseline (665.086 us; speedup 1.0000x reference)
//
#include <hip/hip_runtime.h>
#include <cstdint>

#define N_NODES 172032
#define BATCH   8192
#define NPS     21
#define F_IN    171
#define K1P     192      // K padded to multiple of 32 for layer-1 GEMM
#define F_HID   256
#define F_OUT   128

typedef unsigned short u16;
typedef __attribute__((ext_vector_type(8))) short  bf16x8;
typedef __attribute__((ext_vector_type(4))) float  f32x4;

__device__ inline u16 f2bf(float f) {
    unsigned u = __float_as_uint(f);
    unsigned r = u + 0x7FFFu + ((u >> 16) & 1u);
    return (u16)(r >> 16);
}
__device__ inline float bf2f(u16 h) { return __uint_as_float(((unsigned)h) << 16); }
__device__ inline float lrelu(float v) { return v > 0.f ? v : 0.2f * v; }

// ---- static edge structure (local node ids within a 21-node sample) ----
// node 0 = query, 1..10 = docs, 11..20 = titles
// incoming-edge src lists per dst:
//   dst 0    : srcs 1..10 (docs), then 0 (self)          -> 11 edges, flat base 0
//   dst j    : srcs {0, j+10, j}                         -> 3 edges,  flat base 11+3(j-1)
//   dst 10+j : srcs {j, 10+j}                            -> 2 edges,  flat base 41+2(j-1)
__device__ inline int deg_of(int n)  { return n == 0 ? 11 : (n <= 10 ? 3 : 2); }
__device__ inline int edge_base(int n) { return n == 0 ? 0 : (n <= 10 ? 11 + 3*(n-1) : 41 + 2*(n-11)); }
__device__ inline int src_of(int n, int k) {
    if (n == 0)  return k < 10 ? k + 1 : 0;
    if (n <= 10) return k == 0 ? 0 : (k == 1 ? n + 10 : n);
    return k == 0 ? n - 10 : n;
}

__device__ inline float wave_red(float v) {
    for (int off = 32; off; off >>= 1) v += __shfl_down(v, off);
    return v;
}

// ------------------------------------------------------------------
// K1: build updated x -> out_x (fp32, output 2) and xb (bf16, K-padded)
// grid = N_NODES blocks, 192 threads
// ------------------------------------------------------------------
__global__ void build_x(const int* __restrict__ iptr, const float* __restrict__ x,
                        const int* __restrict__ click, const int* __restrict__ query,
                        const int* __restrict__ docu, const int* __restrict__ title_id,
                        const float* __restrict__ qtab, const float* __restrict__ dtab,
                        const float* __restrict__ ttab, const float* __restrict__ ptab,
                        const float* __restrict__ ctab,
                        float* __restrict__ out_x, u16* __restrict__ xb)
{
    int node = blockIdx.x;
    int t = threadIdx.x;
    int b = node / NPS;
    int p = node - b * NPS;
    int i = iptr[0];
    if (t < F_IN) {
        float v = x[(long)node * F_IN + t];
        if (i == 0) {
            if (p == 0) {                       // query node
                if (t < 160) v = qtab[(long)query[b] * 160 + t];
            } else if (p <= 10) {               // doc node
                int j = p - 1;
                if (t < 160)       v = dtab[(long)docu[b*10 + j] * 160 + t];
                else if (t == 160) v = ptab[j];
                else if (t == 161) v = ctab[click[b]];
            } else {                            // title node
                int j = p - 11;
                if (t < 160) v = ttab[(long)title_id[b*10 + j] * 160 + t];
            }
        } else {
            if (p >= 1 && p <= 10 && t == 161 + i) v = ctab[click[b]];
        }
        out_x[(long)node * F_IN + t] = v;
        xb[(long)node * K1P + t] = f2bf(v);
    } else if (t < K1P) {
        xb[(long)node * K1P + t] = 0;           // zero K-pad
    }
}

// ------------------------------------------------------------------
// weight prep: W1 (256x171 f32) -> W1b (256x192 bf16, zero pad)
//              W2 (128x256 f32) -> W2b (128x256 bf16)
// ------------------------------------------------------------------
__global__ void prep_w(const float* __restrict__ W1, const float* __restrict__ W2,
                       u16* __restrict__ W1b, u16* __restrict__ W2b)
{
    int id = blockIdx.x * 256 + threadIdx.x;
    if (id < 256 * K1P) {
        int r = id / K1P, k = id - r * K1P;
        W1b[id] = (k < F_IN) ? f2bf(W1[r * F_IN + k]) : (u16)0;
    }
    if (id < 128 * 256) W2b[id] = f2bf(W2[id]);
}

// ------------------------------------------------------------------
// bf16 MFMA GEMM: C[m][n] = sum_k A[m][k] * B[n][k]   (B given row-major [n][k])
// BM=64, BN=128, K staged through LDS in KSTAGE chunks. Output bf16.
// block = 256 threads (4 waves in 2x2 grid, each wave 32x64 via 2x4 16x16 frags)
// ------------------------------------------------------------------
template<int KPAD, int KSTAGE>
__global__ __launch_bounds__(256) void gemm_bt(const u16* __restrict__ A, const u16* __restrict__ B,
                                               u16* __restrict__ C, int ldc)
{
    constexpr int SA  = KSTAGE + 8;          // LDS row stride (elements); +8 keeps 16B align, kills conflicts
    constexpr int CPS = KSTAGE / 8;          // 16B chunks per row per stage
    __shared__ __align__(16) u16 Al[64 * SA];
    __shared__ __align__(16) u16 Bl[128 * SA];

    const int m0 = blockIdx.x * 64;
    const int n0 = blockIdx.y * 128;
    const int tid = threadIdx.x;
    const int lane = tid & 63, w = tid >> 6;
    const int wr = w >> 1, wc = w & 1;
    const int lm = lane & 15, lq = lane >> 4;

    f32x4 acc[2][4];
    for (int f = 0; f < 2; ++f)
        for (int g = 0; g < 4; ++g)
            acc[f][g] = (f32x4){0.f, 0.f, 0.f, 0.f};

    for (int ks = 0; ks < KPAD; ks += KSTAGE) {
        if (ks) __syncthreads();
        // stage A tile (64 rows x KSTAGE)
        for (int id = tid; id < 64 * CPS; id += 256) {
            int row = id / CPS, ch = id - row * CPS;
            uint4 vv = *(const uint4*)(A + (long)(m0 + row) * KPAD + ks + ch * 8);
            *(uint4*)(Al + row * SA + ch * 8) = vv;
        }
        // stage B tile (128 rows x KSTAGE)
        for (int id = tid; id < 128 * CPS; id += 256) {
            int row = id / CPS, ch = id - row * CPS;
            uint4 vv = *(const uint4*)(B + (long)(n0 + row) * KPAD + ks + ch * 8);
            *(uint4*)(Bl + row * SA + ch * 8) = vv;
        }
        __syncthreads();

        for (int kb = 0; kb < KSTAGE / 32; ++kb) {
            int koff = kb * 32 + lq * 8;
            bf16x8 a0 = *(const bf16x8*)(Al + (wr*32 +  0 + lm) * SA + koff);
            bf16x8 a1 = *(const bf16x8*)(Al + (wr*32 + 16 + lm) * SA + koff);
            bf16x8 b0 = *(const bf16x8*)(Bl + (wc*64 +  0 + lm) * SA + koff);
            bf16x8 b1 = *(const bf16x8*)(Bl + (wc*64 + 16 + lm) * SA + koff);
            bf16x8 b2 = *(const bf16x8*)(Bl + (wc*64 + 32 + lm) * SA + koff);
            bf16x8 b3 = *(const bf16x8*)(Bl + (wc*64 + 48 + lm) * SA + koff);
            acc[0][0] = __builtin_amdgcn_mfma_f32_16x16x32_bf16(a0, b0, acc[0][0], 0, 0, 0);
            acc[0][1] = __builtin_amdgcn_mfma_f32_16x16x32_bf16(a0, b1, acc[0][1], 0, 0, 0);
            acc[0][2] = __builtin_amdgcn_mfma_f32_16x16x32_bf16(a0, b2, acc[0][2], 0, 0, 0);
            acc[0][3] = __builtin_amdgcn_mfma_f32_16x16x32_bf16(a0, b3, acc[0][3], 0, 0, 0);
            acc[1][0] = __builtin_amdgcn_mfma_f32_16x16x32_bf16(a1, b0, acc[1][0], 0, 0, 0);
            acc[1][1] = __builtin_amdgcn_mfma_f32_16x16x32_bf16(a1, b1, acc[1][1], 0, 0, 0);
            acc[1][2] = __builtin_amdgcn_mfma_f32_16x16x32_bf16(a1, b2, acc[1][2], 0, 0, 0);
            acc[1][3] = __builtin_amdgcn_mfma_f32_16x16x32_bf16(a1, b3, acc[1][3], 0, 0, 0);
        }
    }

    // epilogue: C/D layout col = lane&15, row = (lane>>4)*4 + r   [m89-verified]
    for (int f = 0; f < 2; ++f)
        for (int g = 0; g < 4; ++g)
            for (int r = 0; r < 4; ++r) {
                int row = m0 + wr*32 + f*16 + lq*4 + r;
                int col = n0 + wc*64 + g*16 + lm;
                C[(long)row * ldc + col] = f2bf(acc[f][g][r]);
            }
}

// ------------------------------------------------------------------
// GAT aggregation layer 1: per-sample block (256 threads), F = 256
// y1 = relu( softmax-agg(h1) + b1 )   (bf16 in, bf16 out)
// ------------------------------------------------------------------
__global__ __launch_bounds__(256) void agg1(const u16* __restrict__ h1b,
                                            const float* __restrict__ asrc, const float* __restrict__ adst,
                                            const float* __restrict__ bias, u16* __restrict__ y1b)
{
    __shared__ __align__(16) u16 h[NPS * F_HID];
    __shared__ float s_l[NPS], d_l[NPS], alpha[61];
    int blk = blockIdx.x, tid = threadIdx.x;
    long base = (long)blk * NPS * F_HID;

    for (int id = tid; id < NPS * F_HID / 8; id += 256)
        *(uint4*)(h + id * 8) = *(const uint4*)(h1b + base + id * 8);
    __syncthreads();

    int lane = tid & 63, w = tid >> 6;
    for (int n = w; n < NPS; n += 4) {
        float as_ = 0.f, ad_ = 0.f;
        for (int c = lane; c < F_HID; c += 64) {
            float hv = bf2f(h[n * F_HID + c]);
            as_ += hv * asrc[c];
            ad_ += hv * adst[c];
        }
        as_ = wave_red(as_); ad_ = wave_red(ad_);
        if (lane == 0) { s_l[n] = as_; d_l[n] = ad_; }
    }
    __syncthreads();

    if (tid < NPS) {
        int n = tid, deg = deg_of(n), eb = edge_base(n);
        float dn = d_l[n], m = -1e30f;
        for (int k = 0; k < deg; ++k) m = fmaxf(m, lrelu(s_l[src_of(n,k)] + dn));
        float den = 0.f;
        for (int k = 0; k < deg; ++k) den += expf(lrelu(s_l[src_of(n,k)] + dn) - m);
        float inv = 1.f / den;
        for (int k = 0; k < deg; ++k) alpha[eb + k] = expf(lrelu(s_l[src_of(n,k)] + dn) - m) * inv;
    }
    __syncthreads();

    int c = tid;   // 0..255
    // dst 0
    {
        float a = alpha[10] * bf2f(h[c]);
        for (int j = 1; j <= 10; ++j) a += alpha[j-1] * bf2f(h[j * F_HID + c]);
        y1b[base + c] = f2bf(fmaxf(a + bias[c], 0.f));
    }
    // dst 1..10 (docs)
    for (int j = 1; j <= 10; ++j) {
        int eb = 11 + 3*(j-1);
        float a = alpha[eb]   * bf2f(h[c])
                + alpha[eb+1] * bf2f(h[(j+10) * F_HID + c])
                + alpha[eb+2] * bf2f(h[j * F_HID + c]);
        y1b[base + j * F_HID + c] = f2bf(fmaxf(a + bias[c], 0.f));
    }
    // dst 11..20 (titles)
    for (int j = 1; j <= 10; ++j) {
        int eb = 41 + 2*(j-1);
        float a = alpha[eb]   * bf2f(h[j * F_HID + c])
                + alpha[eb+1] * bf2f(h[(10+j) * F_HID + c]);
        y1b[base + (10+j) * F_HID + c] = f2bf(fmaxf(a + bias[c], 0.f));
    }
}

// ------------------------------------------------------------------
// GAT aggregation layer 2 + readout: per-sample block (128 threads), F = 128
// hidden = agg(g2) + b2 (fp32 -> out, NO relu); y = sigmoid(relu(hidden)·Wl + bl)
// ------------------------------------------------------------------
__global__ __launch_bounds__(128) void agg2(const u16* __restrict__ g2b,
                                            const float* __restrict__ asrc, const float* __restrict__ adst,
                                            const float* __restrict__ bias,
                                            const float* __restrict__ Wl, const float* __restrict__ bl,
                                            float* __restrict__ out_hid, float* __restrict__ out_y)
{
    __shared__ __align__(16) u16 h[NPS * F_OUT];
    __shared__ float s_l[NPS], d_l[NPS], alpha[61];
    __shared__ float hid[NPS * F_OUT];
    int blk = blockIdx.x, tid = threadIdx.x;
    long base = (long)blk * NPS * F_OUT;

    for (int id = tid; id < NPS * F_OUT / 8; id += 128)
        *(uint4*)(h + id * 8) = *(const uint4*)(g2b + base + id * 8);
    __syncthreads();

    int lane = tid & 63, w = tid >> 6;   // 2 waves
    for (int n = w; n < NPS; n += 2) {
        float as_ = 0.f, ad_ = 0.f;
        for (int c = lane; c < F_OUT; c += 64) {
            float hv = bf2f(h[n * F_OUT + c]);
            as_ += hv * asrc[c];
            ad_ += hv * adst[c];
        }
        as_ = wave_red(as_); ad_ = wave_red(ad_);
        if (lane == 0) { s_l[n] = as_; d_l[n] = ad_; }
    }
    __syncthreads();

    if (tid < NPS) {
        int n = tid, deg = deg_of(n), eb = edge_base(n);
        float dn = d_l[n], m = -1e30f;
        for (int k = 0; k < deg; ++k) m = fmaxf(m, lrelu(s_l[src_of(n,k)] + dn));
        float den = 0.f;
        for (int k = 0; k < deg; ++k) den += expf(lrelu(s_l[src_of(n,k)] + dn) - m);
        float inv = 1.f / den;
        for (int k = 0; k < deg; ++k) alpha[eb + k] = expf(lrelu(s_l[src_of(n,k)] + dn) - m) * inv;
    }
    __syncthreads();

    int c = tid;   // 0..127
    float wl = Wl[c];
    {
        float a = alpha[10] * bf2f(h[c]);
        for (int j = 1; j <= 10; ++j) a += alpha[j-1] * bf2f(h[j * F_OUT + c]);
        float hv = a + bias[c];
        out_hid[base + c] = hv;
        hid[c] = fmaxf(hv, 0.f) * wl;
    }
    for (int j = 1; j <= 10; ++j) {
        int eb = 11 + 3*(j-1);
        float a = alpha[eb]   * bf2f(h[c])
                + alpha[eb+1] * bf2f(h[(j+10) * F_OUT + c])
                + alpha[eb+2] * bf2f(h[j * F_OUT + c]);
        float hv = a + bias[c];
        out_hid[base + j * F_OUT + c] = hv;
        hid[j * F_OUT + c] = fmaxf(hv, 0.f) * wl;
    }
    for (int j = 1; j <= 10; ++j) {
        int eb = 41 + 2*(j-1);
        float a = alpha[eb]   * bf2f(h[j * F_OUT + c])
                + alpha[eb+1] * bf2f(h[(10+j) * F_OUT + c]);
        float hv = a + bias[c];
        out_hid[base + (10+j) * F_OUT + c] = hv;
        hid[(10+j) * F_OUT + c] = fmaxf(hv, 0.f) * wl;
    }
    __syncthreads();

    float bl0 = bl[0];
    for (int n = w; n < NPS; n += 2) {
        float v = hid[n * F_OUT + lane] + hid[n * F_OUT + lane + 64];
        v = wave_red(v);
        if (lane == 0) out_y[(long)blk * NPS + n] = 1.f / (1.f + expf(-(v + bl0)));
    }
}

// ------------------------------------------------------------------
extern "C" void kernel_launch(void* const* d_in, const int* in_sizes, int n_in,
                              void* d_out, int out_size, void* d_ws, size_t ws_size,
                              hipStream_t stream) {
    const int*   ip    = (const int*)  d_in[0];
    const float* x     = (const float*)d_in[1];
    // d_in[2] edge_index, d_in[3] doc_id: structure is static, recomputed on device
    const int*   click = (const int*)  d_in[4];
    const int*   query = (const int*)  d_in[5];
    const int*   docu  = (const int*)  d_in[6];
    const int*   title = (const int*)  d_in[7];
    const float* qtab  = (const float*)d_in[8];
    const float* dtab  = (const float*)d_in[9];
    const float* ttab  = (const float*)d_in[10];
    const float* ptab  = (const float*)d_in[11];
    const float* ctab  = (const float*)d_in[12];
    const float* W1    = (const float*)d_in[13];
    const float* as1   = (const float*)d_in[14];
    const float* ad1   = (const float*)d_in[15];
    const float* b1    = (const float*)d_in[16];
    const float* W2    = (const float*)d_in[17];
    const float* as2   = (const float*)d_in[18];
    const float* ad2   = (const float*)d_in[19];
    const float* b2    = (const float*)d_in[20];
    const float* Wl    = (const float*)d_in[21];
    const float* bl    = (const float*)d_in[22];

    float* out_hid = (float*)d_out;                       // N x 128
    float* out_y   = out_hid + (long)N_NODES * F_OUT;     // N
    float* out_x   = out_y + N_NODES;                     // N x 171

    // workspace layout (u16 elements), with reuse:
    //   region A [0, 44040192)          : h1b (Nx256) then g2b (Nx128)
    //   region B [44040192, 88080384)   : xb (Nx192) then y1b (Nx256)
    //   region C [88080384, ...)        : W1b (256x192), W2b (128x256)
    // total = 176,324,608 bytes
    u16* h1b = (u16*)d_ws;
    u16* g2b = h1b;
    u16* xb  = h1b + 44040192L;
    u16* y1b = xb;
    u16* W1b = h1b + 88080384L;
    u16* W2b = W1b + 256 * K1P;

    build_x<<<N_NODES, 192, 0, stream>>>(ip, x, click, query, docu, title,
                                         qtab, dtab, ttab, ptab, ctab, out_x, xb);
    prep_w<<<192, 256, 0, stream>>>(W1, W2, W1b, W2b);
    gemm_bt<K1P, 96><<<dim3(N_NODES / 64, 2), 256, 0, stream>>>(xb, W1b, h1b, F_HID);
    agg1<<<BATCH, 256, 0, stream>>>(h1b, as1, ad1, b1, y1b);
    gemm_bt<F_HID, 128><<<dim3(N_NODES / 64, 1), 256, 0, stream>>>(y1b, W2b, g2b, F_OUT);
    agg2<<<BATCH, 128, 0, stream>>>(g2b, as2, ad2, b2, Wl, bl, out_hid, out_y);
}

// Round 2
// 589.014 us; speedup vs baseline: 1.1292x; 1.1292x over previous
//
#include <hip/hip_runtime.h>
#include <cstdint>

#define N_NODES 172032
#define BATCH   8192
#define NPS     21
#define F_IN    171
#define K1P     192      // K padded to multiple of 32 for layer-1 GEMM
#define F_HID   256
#define F_OUT   128
#define SX_F    (NPS * F_IN)   // 3591 floats per sample in x/out_x
#define SXB     (NPS * K1P)    // 4032 bf16 per sample in xb

typedef unsigned short u16;
typedef __attribute__((ext_vector_type(8))) short  bf16x8;
typedef __attribute__((ext_vector_type(4))) float  f32x4;

__device__ inline u16 f2bf(float f) {
    unsigned u = __float_as_uint(f);
    unsigned r = u + 0x7FFFu + ((u >> 16) & 1u);
    return (u16)(r >> 16);
}
__device__ inline float bf2f(u16 h) { return __uint_as_float(((unsigned)h) << 16); }
__device__ inline float lrelu(float v) { return v > 0.f ? v : 0.2f * v; }

// ---- static edge structure (local node ids within a 21-node sample) ----
// node 0 = query, 1..10 = docs, 11..20 = titles
__device__ inline int deg_of(int n)  { return n == 0 ? 11 : (n <= 10 ? 3 : 2); }
__device__ inline int edge_base(int n) { return n == 0 ? 0 : (n <= 10 ? 11 + 3*(n-1) : 41 + 2*(n-11)); }
__device__ inline int src_of(int n, int k) {
    if (n == 0)  return k < 10 ? k + 1 : 0;
    if (n <= 10) return k == 0 ? 0 : (k == 1 ? n + 10 : n);
    return k == 0 ? n - 10 : n;
}

__device__ inline float wave_red(float v) {
    for (int off = 32; off; off >>= 1) v += __shfl_down(v, off);
    return v;
}

// ------------------------------------------------------------------
// build_x v2: one block per SAMPLE. Assemble 21x171 fp32 in LDS from
// table gathers + x tail (i==0 reads only cols 160..170 of x), then
// bulk write: out_x via aligned float4, xb via packed 8xbf16 uint4.
// ------------------------------------------------------------------
__global__ __launch_bounds__(256) void build_x(const int* __restrict__ iptr, const float* __restrict__ x,
                        const int* __restrict__ click, const int* __restrict__ query,
                        const int* __restrict__ docu, const int* __restrict__ title_id,
                        const float* __restrict__ qtab, const float* __restrict__ dtab,
                        const float* __restrict__ ttab, const float* __restrict__ ptab,
                        const float* __restrict__ ctab,
                        float* __restrict__ out_x, u16* __restrict__ xb)
{
    __shared__ float sx[SX_F];
    __shared__ int   dz[10], tz[10], s_q;
    __shared__ float s_clk;

    const int s   = blockIdx.x;
    const int tid = threadIdx.x;
    const int i   = iptr[0];
    const long xbase = (long)s * SX_F;

    if (tid < 10)       dz[tid]      = docu[s*10 + tid];
    else if (tid < 20)  tz[tid - 10] = title_id[s*10 + tid - 10];
    else if (tid == 20) s_q          = query[s];
    else if (tid == 21) s_clk        = ctab[click[s]];
    __syncthreads();

    if (i == 0) {
        for (int idx = tid; idx < SX_F; idx += 256) {
            int p = idx / F_IN;            // compile-time const divisor -> magic mul
            int c = idx - p * F_IN;
            float v;
            if (c >= 160) {
                if (p >= 1 && p <= 10 && c == 160)      v = ptab[p - 1];
                else if (p >= 1 && p <= 10 && c == 161) v = s_clk;
                else                                     v = x[xbase + idx];
            } else {
                if (p == 0)       v = qtab[(long)s_q * 160 + c];
                else if (p <= 10) v = dtab[(long)dz[p-1] * 160 + c];
                else              v = ttab[(long)tz[p-11] * 160 + c];
            }
            sx[idx] = v;
        }
    } else {
        for (int idx = tid; idx < SX_F; idx += 256) {
            int p = idx / F_IN;
            int c = idx - p * F_IN;
            float v = x[xbase + idx];
            if (p >= 1 && p <= 10 && c == 161 + i) v = s_clk;
            sx[idx] = v;
        }
    }
    __syncthreads();

    // ---- out_x: flat region [xbase, xbase+3591), float4 on aligned interior ----
    {
        int r    = (int)(xbase & 3);
        int head = (4 - r) & 3;
        if (tid < head) out_x[xbase + tid] = sx[tid];
        int n4 = (SX_F - head) >> 2;
        for (int id = tid; id < n4; id += 256) {
            int o = head + id * 4;
            float4 v = make_float4(sx[o], sx[o+1], sx[o+2], sx[o+3]);
            *(float4*)(out_x + xbase + o) = v;
        }
        int done = head + n4 * 4;
        int tail = SX_F - done;
        if (tid < tail) out_x[xbase + done + tid] = sx[done + tid];
    }

    // ---- xb: bf16, K-padded to 192/row; sample region 16B-aligned ----
    {
        u16* xbs = xb + (long)s * SXB;
        for (int id = tid; id < SXB / 8; id += 256) {
            int k0 = id * 8;
            int node = k0 / K1P;
            int kk   = k0 - node * K1P;
            union { u16 h[8]; uint4 v; } u;
            #pragma unroll
            for (int j = 0; j < 8; ++j) {
                int c = kk + j;
                u.h[j] = (c < F_IN) ? f2bf(sx[node * F_IN + c]) : (u16)0;
            }
            *(uint4*)(xbs + k0) = u.v;
        }
    }
}

// ------------------------------------------------------------------
// weight prep: W1 (256x171 f32) -> W1b (256x192 bf16, zero pad)
//              W2 (128x256 f32) -> W2b (128x256 bf16)
// ------------------------------------------------------------------
__global__ void prep_w(const float* __restrict__ W1, const float* __restrict__ W2,
                       u16* __restrict__ W1b, u16* __restrict__ W2b)
{
    int id = blockIdx.x * 256 + threadIdx.x;
    if (id < 256 * K1P) {
        int r = id / K1P, k = id - r * K1P;
        W1b[id] = (k < F_IN) ? f2bf(W1[r * F_IN + k]) : (u16)0;
    }
    if (id < 128 * 256) W2b[id] = f2bf(W2[id]);
}

// ------------------------------------------------------------------
// bf16 MFMA GEMM: C[m][n] = sum_k A[m][k] * B[n][k]   (B given row-major [n][k])
// BM=64, BN=128, K staged through LDS in KSTAGE chunks. Output bf16.
// ------------------------------------------------------------------
template<int KPAD, int KSTAGE>
__global__ __launch_bounds__(256) void gemm_bt(const u16* __restrict__ A, const u16* __restrict__ B,
                                               u16* __restrict__ C, int ldc)
{
    constexpr int SA  = KSTAGE + 8;
    constexpr int CPS = KSTAGE / 8;
    __shared__ __align__(16) u16 Al[64 * SA];
    __shared__ __align__(16) u16 Bl[128 * SA];

    const int m0 = blockIdx.x * 64;
    const int n0 = blockIdx.y * 128;
    const int tid = threadIdx.x;
    const int lane = tid & 63, w = tid >> 6;
    const int wr = w >> 1, wc = w & 1;
    const int lm = lane & 15, lq = lane >> 4;

    f32x4 acc[2][4];
    for (int f = 0; f < 2; ++f)
        for (int g = 0; g < 4; ++g)
            acc[f][g] = (f32x4){0.f, 0.f, 0.f, 0.f};

    for (int ks = 0; ks < KPAD; ks += KSTAGE) {
        if (ks) __syncthreads();
        for (int id = tid; id < 64 * CPS; id += 256) {
            int row = id / CPS, ch = id - row * CPS;
            uint4 vv = *(const uint4*)(A + (long)(m0 + row) * KPAD + ks + ch * 8);
            *(uint4*)(Al + row * SA + ch * 8) = vv;
        }
        for (int id = tid; id < 128 * CPS; id += 256) {
            int row = id / CPS, ch = id - row * CPS;
            uint4 vv = *(const uint4*)(B + (long)(n0 + row) * KPAD + ks + ch * 8);
            *(uint4*)(Bl + row * SA + ch * 8) = vv;
        }
        __syncthreads();

        for (int kb = 0; kb < KSTAGE / 32; ++kb) {
            int koff = kb * 32 + lq * 8;
            bf16x8 a0 = *(const bf16x8*)(Al + (wr*32 +  0 + lm) * SA + koff);
            bf16x8 a1 = *(const bf16x8*)(Al + (wr*32 + 16 + lm) * SA + koff);
            bf16x8 b0 = *(const bf16x8*)(Bl + (wc*64 +  0 + lm) * SA + koff);
            bf16x8 b1 = *(const bf16x8*)(Bl + (wc*64 + 16 + lm) * SA + koff);
            bf16x8 b2 = *(const bf16x8*)(Bl + (wc*64 + 32 + lm) * SA + koff);
            bf16x8 b3 = *(const bf16x8*)(Bl + (wc*64 + 48 + lm) * SA + koff);
            acc[0][0] = __builtin_amdgcn_mfma_f32_16x16x32_bf16(a0, b0, acc[0][0], 0, 0, 0);
            acc[0][1] = __builtin_amdgcn_mfma_f32_16x16x32_bf16(a0, b1, acc[0][1], 0, 0, 0);
            acc[0][2] = __builtin_amdgcn_mfma_f32_16x16x32_bf16(a0, b2, acc[0][2], 0, 0, 0);
            acc[0][3] = __builtin_amdgcn_mfma_f32_16x16x32_bf16(a0, b3, acc[0][3], 0, 0, 0);
            acc[1][0] = __builtin_amdgcn_mfma_f32_16x16x32_bf16(a1, b0, acc[1][0], 0, 0, 0);
            acc[1][1] = __builtin_amdgcn_mfma_f32_16x16x32_bf16(a1, b1, acc[1][1], 0, 0, 0);
            acc[1][2] = __builtin_amdgcn_mfma_f32_16x16x32_bf16(a1, b2, acc[1][2], 0, 0, 0);
            acc[1][3] = __builtin_amdgcn_mfma_f32_16x16x32_bf16(a1, b3, acc[1][3], 0, 0, 0);
        }
    }

    for (int f = 0; f < 2; ++f)
        for (int g = 0; g < 4; ++g)
            for (int r = 0; r < 4; ++r) {
                int row = m0 + wr*32 + f*16 + lq*4 + r;
                int col = n0 + wc*64 + g*16 + lm;
                C[(long)row * ldc + col] = f2bf(acc[f][g][r]);
            }
}

// ------------------------------------------------------------------
// GAT aggregation layer 1: per-sample block (256 threads), F = 256
// ------------------------------------------------------------------
__global__ __launch_bounds__(256) void agg1(const u16* __restrict__ h1b,
                                            const float* __restrict__ asrc, const float* __restrict__ adst,
                                            const float* __restrict__ bias, u16* __restrict__ y1b)
{
    __shared__ __align__(16) u16 h[NPS * F_HID];
    __shared__ float s_l[NPS], d_l[NPS], alpha[61];
    int blk = blockIdx.x, tid = threadIdx.x;
    long base = (long)blk * NPS * F_HID;

    for (int id = tid; id < NPS * F_HID / 8; id += 256)
        *(uint4*)(h + id * 8) = *(const uint4*)(h1b + base + id * 8);
    __syncthreads();

    int lane = tid & 63, w = tid >> 6;
    for (int n = w; n < NPS; n += 4) {
        float as_ = 0.f, ad_ = 0.f;
        for (int c = lane; c < F_HID; c += 64) {
            float hv = bf2f(h[n * F_HID + c]);
            as_ += hv * asrc[c];
            ad_ += hv * adst[c];
        }
        as_ = wave_red(as_); ad_ = wave_red(ad_);
        if (lane == 0) { s_l[n] = as_; d_l[n] = ad_; }
    }
    __syncthreads();

    if (tid < NPS) {
        int n = tid, deg = deg_of(n), eb = edge_base(n);
        float dn = d_l[n], m = -1e30f;
        for (int k = 0; k < deg; ++k) m = fmaxf(m, lrelu(s_l[src_of(n,k)] + dn));
        float den = 0.f;
        for (int k = 0; k < deg; ++k) den += expf(lrelu(s_l[src_of(n,k)] + dn) - m);
        float inv = 1.f / den;
        for (int k = 0; k < deg; ++k) alpha[eb + k] = expf(lrelu(s_l[src_of(n,k)] + dn) - m) * inv;
    }
    __syncthreads();

    int c = tid;
    {
        float a = alpha[10] * bf2f(h[c]);
        for (int j = 1; j <= 10; ++j) a += alpha[j-1] * bf2f(h[j * F_HID + c]);
        y1b[base + c] = f2bf(fmaxf(a + bias[c], 0.f));
    }
    for (int j = 1; j <= 10; ++j) {
        int eb = 11 + 3*(j-1);
        float a = alpha[eb]   * bf2f(h[c])
                + alpha[eb+1] * bf2f(h[(j+10) * F_HID + c])
                + alpha[eb+2] * bf2f(h[j * F_HID + c]);
        y1b[base + j * F_HID + c] = f2bf(fmaxf(a + bias[c], 0.f));
    }
    for (int j = 1; j <= 10; ++j) {
        int eb = 41 + 2*(j-1);
        float a = alpha[eb]   * bf2f(h[j * F_HID + c])
                + alpha[eb+1] * bf2f(h[(10+j) * F_HID + c]);
        y1b[base + (10+j) * F_HID + c] = f2bf(fmaxf(a + bias[c], 0.f));
    }
}

// ------------------------------------------------------------------
// GAT aggregation layer 2 + readout: per-sample block (128 threads), F = 128
// ------------------------------------------------------------------
__global__ __launch_bounds__(128) void agg2(const u16* __restrict__ g2b,
                                            const float* __restrict__ asrc, const float* __restrict__ adst,
                                            const float* __restrict__ bias,
                                            const float* __restrict__ Wl, const float* __restrict__ bl,
                                            float* __restrict__ out_hid, float* __restrict__ out_y)
{
    __shared__ __align__(16) u16 h[NPS * F_OUT];
    __shared__ float s_l[NPS], d_l[NPS], alpha[61];
    __shared__ float hid[NPS * F_OUT];
    int blk = blockIdx.x, tid = threadIdx.x;
    long base = (long)blk * NPS * F_OUT;

    for (int id = tid; id < NPS * F_OUT / 8; id += 128)
        *(uint4*)(h + id * 8) = *(const uint4*)(g2b + base + id * 8);
    __syncthreads();

    int lane = tid & 63, w = tid >> 6;
    for (int n = w; n < NPS; n += 2) {
        float as_ = 0.f, ad_ = 0.f;
        for (int c = lane; c < F_OUT; c += 64) {
            float hv = bf2f(h[n * F_OUT + c]);
            as_ += hv * asrc[c];
            ad_ += hv * adst[c];
        }
        as_ = wave_red(as_); ad_ = wave_red(ad_);
        if (lane == 0) { s_l[n] = as_; d_l[n] = ad_; }
    }
    __syncthreads();

    if (tid < NPS) {
        int n = tid, deg = deg_of(n), eb = edge_base(n);
        float dn = d_l[n], m = -1e30f;
        for (int k = 0; k < deg; ++k) m = fmaxf(m, lrelu(s_l[src_of(n,k)] + dn));
        float den = 0.f;
        for (int k = 0; k < deg; ++k) den += expf(lrelu(s_l[src_of(n,k)] + dn) - m);
        float inv = 1.f / den;
        for (int k = 0; k < deg; ++k) alpha[eb + k] = expf(lrelu(s_l[src_of(n,k)] + dn) - m) * inv;
    }
    __syncthreads();

    int c = tid;
    float wl = Wl[c];
    {
        float a = alpha[10] * bf2f(h[c]);
        for (int j = 1; j <= 10; ++j) a += alpha[j-1] * bf2f(h[j * F_OUT + c]);
        float hv = a + bias[c];
        out_hid[base + c] = hv;
        hid[c] = fmaxf(hv, 0.f) * wl;
    }
    for (int j = 1; j <= 10; ++j) {
        int eb = 11 + 3*(j-1);
        float a = alpha[eb]   * bf2f(h[c])
                + alpha[eb+1] * bf2f(h[(j+10) * F_OUT + c])
                + alpha[eb+2] * bf2f(h[j * F_OUT + c]);
        float hv = a + bias[c];
        out_hid[base + j * F_OUT + c] = hv;
        hid[j * F_OUT + c] = fmaxf(hv, 0.f) * wl;
    }
    for (int j = 1; j <= 10; ++j) {
        int eb = 41 + 2*(j-1);
        float a = alpha[eb]   * bf2f(h[j * F_OUT + c])
                + alpha[eb+1] * bf2f(h[(10+j) * F_OUT + c]);
        float hv = a + bias[c];
        out_hid[base + (10+j) * F_OUT + c] = hv;
        hid[(10+j) * F_OUT + c] = fmaxf(hv, 0.f) * wl;
    }
    __syncthreads();

    float bl0 = bl[0];
    for (int n = w; n < NPS; n += 2) {
        float v = hid[n * F_OUT + lane] + hid[n * F_OUT + lane + 64];
        v = wave_red(v);
        if (lane == 0) out_y[(long)blk * NPS + n] = 1.f / (1.f + expf(-(v + bl0)));
    }
}

// ------------------------------------------------------------------
extern "C" void kernel_launch(void* const* d_in, const int* in_sizes, int n_in,
                              void* d_out, int out_size, void* d_ws, size_t ws_size,
                              hipStream_t stream) {
    const int*   ip    = (const int*)  d_in[0];
    const float* x     = (const float*)d_in[1];
    const int*   click = (const int*)  d_in[4];
    const int*   query = (const int*)  d_in[5];
    const int*   docu  = (const int*)  d_in[6];
    const int*   title = (const int*)  d_in[7];
    const float* qtab  = (const float*)d_in[8];
    const float* dtab  = (const float*)d_in[9];
    const float* ttab  = (const float*)d_in[10];
    const float* ptab  = (const float*)d_in[11];
    const float* ctab  = (const float*)d_in[12];
    const float* W1    = (const float*)d_in[13];
    const float* as1   = (const float*)d_in[14];
    const float* ad1   = (const float*)d_in[15];
    const float* b1    = (const float*)d_in[16];
    const float* W2    = (const float*)d_in[17];
    const float* as2   = (const float*)d_in[18];
    const float* ad2   = (const float*)d_in[19];
    const float* b2    = (const float*)d_in[20];
    const float* Wl    = (const float*)d_in[21];
    const float* bl    = (const float*)d_in[22];

    float* out_hid = (float*)d_out;
    float* out_y   = out_hid + (long)N_NODES * F_OUT;
    float* out_x   = out_y + N_NODES;

    u16* h1b = (u16*)d_ws;
    u16* g2b = h1b;
    u16* xb  = h1b + 44040192L;
    u16* y1b = xb;
    u16* W1b = h1b + 88080384L;
    u16* W2b = W1b + 256 * K1P;

    build_x<<<BATCH, 256, 0, stream>>>(ip, x, click, query, docu, title,
                                       qtab, dtab, ttab, ptab, ctab, out_x, xb);
    prep_w<<<192, 256, 0, stream>>>(W1, W2, W1b, W2b);
    gemm_bt<K1P, 96><<<dim3(N_NODES / 64, 2), 256, 0, stream>>>(xb, W1b, h1b, F_HID);
    agg1<<<BATCH, 256, 0, stream>>>(h1b, as1, ad1, b1, y1b);
    gemm_bt<F_HID, 128><<<dim3(N_NODES / 64, 1), 256, 0, stream>>>(y1b, W2b, g2b, F_OUT);
    agg2<<<BATCH, 128, 0, stream>>>(g2b, as2, ad2, b2, Wl, bl, out_hid, out_y);
}